// Round 1
// baseline (176.633 us; speedup 1.0000x reference)
//
#include <hip/hip_runtime.h>

// BERT lattice embedding: ragged segment mean-pool.
// hidden: [B,S,H] f32, word_ids: [B,S] i32 (non-decreasing per sample),
// out: [B,T,H] f32 with out[b,t,:] = mean of hidden[b,s,:] over s where
// word_ids[b,s]==t (zeros if no such s).
//
// word_ids sorted per row => segments are contiguous runs; each output row
// binary-searches its [start,end) range. One wave (64 threads) per output row:
// lane i handles float4 indices {i, i+64, i+128} of the 768-float row
// (768 = 192 float4 = 64 lanes x 3). Fully coalesced 16B/lane.

#define BB 64
#define SS 512
#define HH 768
#define TT 400

__global__ __launch_bounds__(64) void bert_lattice_pool_kernel(
    const float* __restrict__ hidden,
    const int* __restrict__ word_ids,
    float* __restrict__ out)
{
    const int bt = blockIdx.x;          // b*TT + t
    const int b  = bt / TT;
    const int t  = bt - b * TT;

    const int* wrow = word_ids + b * SS;

    // lower_bound(t): first s with wrow[s] >= t   (wave-uniform, ~9 cached reads)
    int lo = 0, hi = SS;
    while (lo < hi) {
        int mid = (lo + hi) >> 1;
        if (wrow[mid] < t) lo = mid + 1; else hi = mid;
    }
    const int start = lo;
    // upper_bound(t): first s with wrow[s] > t
    hi = SS;
    while (lo < hi) {
        int mid = (lo + hi) >> 1;
        if (wrow[mid] <= t) lo = mid + 1; else hi = mid;
    }
    const int end   = lo;
    const int count = end - start;

    const int lane = threadIdx.x;       // 0..63

    float4 acc0 = make_float4(0.f, 0.f, 0.f, 0.f);
    float4 acc1 = make_float4(0.f, 0.f, 0.f, 0.f);
    float4 acc2 = make_float4(0.f, 0.f, 0.f, 0.f);

    for (int s = start; s < end; ++s) {
        const float4* p =
            reinterpret_cast<const float4*>(hidden + ((size_t)b * SS + s) * HH);
        float4 v0 = p[lane];
        float4 v1 = p[lane + 64];
        float4 v2 = p[lane + 128];
        acc0.x += v0.x; acc0.y += v0.y; acc0.z += v0.z; acc0.w += v0.w;
        acc1.x += v1.x; acc1.y += v1.y; acc1.z += v1.z; acc1.w += v1.w;
        acc2.x += v2.x; acc2.y += v2.y; acc2.z += v2.z; acc2.w += v2.w;
    }

    const float inv = 1.0f / (float)(count > 0 ? count : 1);

    float4* o = reinterpret_cast<float4*>(out + ((size_t)b * TT + t) * HH);
    float4 r0 = make_float4(acc0.x * inv, acc0.y * inv, acc0.z * inv, acc0.w * inv);
    float4 r1 = make_float4(acc1.x * inv, acc1.y * inv, acc1.z * inv, acc1.w * inv);
    float4 r2 = make_float4(acc2.x * inv, acc2.y * inv, acc2.z * inv, acc2.w * inv);
    o[lane]       = r0;
    o[lane + 64]  = r1;
    o[lane + 128] = r2;
}

extern "C" void kernel_launch(void* const* d_in, const int* in_sizes, int n_in,
                              void* d_out, int out_size, void* d_ws, size_t ws_size,
                              hipStream_t stream) {
    (void)in_sizes; (void)n_in; (void)d_ws; (void)ws_size; (void)out_size;
    const float* hidden   = (const float*)d_in[0];
    const int*   word_ids = (const int*)d_in[1];
    float*       out      = (float*)d_out;

    // One wave per output (b, t) row.
    dim3 grid(BB * TT);
    dim3 block(64);
    bert_lattice_pool_kernel<<<grid, block, 0, stream>>>(hidden, word_ids, out);
}